// Round 6
// baseline (1102.177 us; speedup 1.0000x reference)
//
#include <hip/hip_runtime.h>

// ---------------- types / helpers ----------------
typedef float  f32x4  __attribute__((ext_vector_type(4)));
typedef __bf16 bf16x4 __attribute__((ext_vector_type(4)));
typedef __bf16 bf16x8 __attribute__((ext_vector_type(8)));

#define MFMA16(a,b,c) __builtin_amdgcn_mfma_f32_16x16x32_bf16((a),(b),(c),0,0,0)

__device__ __forceinline__ void async_copy16(void* lds, const void* gmem) {
  __builtin_amdgcn_global_load_lds(
      (const __attribute__((address_space(1))) void*)gmem,
      (__attribute__((address_space(3))) void*)lds, 16, 0, 0);
}

template<int N> __device__ __forceinline__ void vmcnt_gate() {
  if constexpr (N == 8) asm volatile("s_waitcnt vmcnt(8)" ::: "memory");
  else if constexpr (N == 6) asm volatile("s_waitcnt vmcnt(6)" ::: "memory");
  else if constexpr (N == 4) asm volatile("s_waitcnt vmcnt(4)" ::: "memory");
  else if constexpr (N == 2) asm volatile("s_waitcnt vmcnt(2)" ::: "memory");
  else if constexpr (N == 0) asm volatile("s_waitcnt vmcnt(0)" ::: "memory");
  __builtin_amdgcn_sched_barrier(0);
}

// counted lgkm wait: drains all ds_reads OLDER than the N just issued (rule #18 fences)
#define LGKM(N) do { __builtin_amdgcn_sched_barrier(0); \
                     asm volatile("s_waitcnt lgkmcnt(" #N ")" ::: "memory"); \
                     __builtin_amdgcn_sched_barrier(0); } while (0)

#define BARRIER do { __builtin_amdgcn_sched_barrier(0); \
                     __builtin_amdgcn_s_barrier(); \
                     __builtin_amdgcn_sched_barrier(0); } while (0)

// ---------------- convert f32 -> bf16 (vectorized x4) ----------------
__global__ __launch_bounds__(256) void convert_kernel(const float* __restrict__ in,
                                                      __bf16* __restrict__ out, size_t n4) {
  size_t i = (size_t)blockIdx.x * 256 + threadIdx.x;
  if (i >= n4) return;
  f32x4 v = *(const f32x4*)(in + i * 4);
  bf16x4 o;
  #pragma unroll
  for (int j = 0; j < 4; ++j) o[j] = (__bf16)v[j];
  *(bf16x4*)(out + i * 4) = o;
}

// ---------------- transpose + convert: in f32 (R,C) -> out bf16 (C,R) ----------------
__global__ __launch_bounds__(256) void transpose_kernel(const float* __restrict__ in,
                                                        __bf16* __restrict__ out, int R, int C) {
  __shared__ float tile[32][33];
  int bx = blockIdx.x, by = blockIdx.y;
  int tx = threadIdx.x & 31, ty0 = threadIdx.x >> 5;
  #pragma unroll
  for (int i = 0; i < 4; ++i) {
    int r = by * 32 + ty0 + i * 8;
    tile[ty0 + i * 8][tx] = in[(size_t)r * C + bx * 32 + tx];
  }
  __syncthreads();
  #pragma unroll
  for (int i = 0; i < 4; ++i) {
    int c = bx * 32 + ty0 + i * 8;
    out[(size_t)c * R + by * 32 + tx] = (__bf16)tile[tx][ty0 + i * 8];
  }
}

// ---------------- 128x128 pipelined bf16 GEMM, 2 blocks/CU ----------------
// C(M,N) = A(M,K) * Bt(N,K)^T. 256 threads = 4 waves (2M x 2N), wave out 64x64 =
// acc[4][4] f32x4. LDS 64KB: 2 bufs x {A[128][64], B[128][64]} bf16, XOR-swizzled.
// RATIONALE (R6): three K-loop schedules plateaued at 40-46% MfmaUtil with ONE
// 8-wave barrier group per CU (128KB LDS blocks a 2nd block). 64KB blocks -> TWO
// independent workgroups co-resident per CU: when one drains a barrier/vmcnt, the
// other's waves fill the MFMA+LDS pipes (m114 cross-wave overlap).
// K-loop = 1:1 clone of the verified R3 schedule (978us, race-proven):
//   block0: R1=aB(h1,k0)[2]; LATE(tau+1->nbuf A q1,q3); LGKM(2) drains R0; M0=aA*bA
//   block1: R2=aA(h0,k1)[2]+bB(k1)[4];                   LGKM(6) drains R1; M1=aB*bA
//   block2: R3=aB(h1,k1)[2];                             LGKM(2) drains R2; M2=aA*bB; G2
//   block3: R0'=aA+bA(nbuf)[6]; EARLY(tau+2->buf A q0,q2 + B q0..3);
//                                                        LGKM(6) drains R3; M3=aB*bB; G3
// Quanta = 32 rows (4 waves x 8 rows). Reader/region map identical to R3's proof:
// LATE regions (A q1,q3) read only by R1/R3 (aB rows wm*64+32..63 = q1|q3); EARLY
// regions (A q0,q2 + B) read by R0/R2 (aA rows = q0|q2) and bA/bB. Gates BEFORE
// their barrier (R2 lesson): G2=vmcnt(2) [EARLY(tau+1) landed -> block3 nbuf reads],
// G3=vmcnt(6) [LATE(tau+1) landed -> next block0 aB]. Tail: T-2 G3=0; T-1 no gates.
// MODE epilogues: 0=plain, 2=V permuted store, 1=RoPE fused. MODE1 with BN=128:
// colmap re-based per 256-row head: boff=n0&255; src row = headbase+colmap(boff+s);
// pair (nt,nt+1) holds (d, d+128), d = ((boff>>5)+2*wn+(nt>>1))*16+lo (intra-thread).

template<bool REMAP>
__device__ __forceinline__ void stage_q(__bf16* region, int qrow, const __bf16* src,
                                        int K, int boff, int w, int l) {
  int s = qrow + w * 8 + (l >> 3);
  int g = boff + s;
  int gr = REMAP ? (((g >> 5) << 4) | (g & 15) | (((g >> 4) & 1) << 7)) : s;
  async_copy16(region + (size_t)(qrow + w * 8) * 64,
               src + (size_t)gr * K + (((l & 7) ^ (s & 7)) << 3));
}

template<bool LATE, bool EARLY, bool NEXT, int G2, int G3, bool BMAP>
__device__ __forceinline__ void tile_body(__bf16* smem,
                                          const __bf16* Apan, const __bf16* Bpan,
                                          int K, int boff, int tau, int wm, int wn,
                                          int lo, int hi, int w, int l,
                                          bf16x8 (&aA)[2], bf16x8 (&aB)[2],
                                          bf16x8 (&bA)[4], bf16x8 (&bB)[4],
                                          f32x4 (&acc)[4][4]) {
  const int buf = tau & 1;
  __bf16* Ab = smem + buf * 16384;
  __bf16* Bb = Ab + 8192;
  __bf16* An = smem + (buf ^ 1) * 16384;
  __bf16* Bn = An + 8192;

  // ---- block0: R1 = aB(h1,k0)[buf]; S0 = LATE; LGKM(2) drains R0; M0 = aA*bA
  #pragma unroll
  for (int t = 0; t < 2; ++t) {
    int ra = wm * 64 + 32 + t * 16 + lo;
    aB[t] = *(const bf16x8*)(Ab + (size_t)ra * 64 + ((hi ^ (ra & 7)) << 3));
  }
  if constexpr (LATE) {
    const __bf16* Ap1 = Apan + (size_t)(tau + 1) * 64;
    stage_q<false>(An, 32, Ap1, K, 0, w, l);   // A q1
    stage_q<false>(An, 96, Ap1, K, 0, w, l);   // A q3
  }
  LGKM(2);
  __builtin_amdgcn_s_setprio(1);
  #pragma unroll
  for (int mt = 0; mt < 2; ++mt)
    #pragma unroll
    for (int nt = 0; nt < 4; ++nt)
      acc[mt][nt] = MFMA16(aA[mt], bA[nt], acc[mt][nt]);
  __builtin_amdgcn_s_setprio(0);
  BARRIER;

  // ---- block1: R2 = aA(h0,k1) + bB(k1) [buf]; LGKM(6) drains R1; M1 = aB*bA
  #pragma unroll
  for (int t = 0; t < 2; ++t) {
    int ra = wm * 64 + t * 16 + lo;
    aA[t] = *(const bf16x8*)(Ab + (size_t)ra * 64 + (((4 + hi) ^ (ra & 7)) << 3));
  }
  #pragma unroll
  for (int t = 0; t < 4; ++t) {
    int rb = wn * 64 + t * 16 + lo;
    bB[t] = *(const bf16x8*)(Bb + (size_t)rb * 64 + (((4 + hi) ^ (rb & 7)) << 3));
  }
  LGKM(6);
  __builtin_amdgcn_s_setprio(1);
  #pragma unroll
  for (int mt = 0; mt < 2; ++mt)
    #pragma unroll
    for (int nt = 0; nt < 4; ++nt)
      acc[2 + mt][nt] = MFMA16(aB[mt], bA[nt], acc[2 + mt][nt]);
  __builtin_amdgcn_s_setprio(0);
  BARRIER;

  // ---- block2: R3 = aB(h1,k1)[buf]; LGKM(2) drains R2; M2 = aA*bB; G2 gate; bar
  #pragma unroll
  for (int t = 0; t < 2; ++t) {
    int ra = wm * 64 + 32 + t * 16 + lo;
    aB[t] = *(const bf16x8*)(Ab + (size_t)ra * 64 + (((4 + hi) ^ (ra & 7)) << 3));
  }
  LGKM(2);
  __builtin_amdgcn_s_setprio(1);
  #pragma unroll
  for (int mt = 0; mt < 2; ++mt)
    #pragma unroll
    for (int nt = 0; nt < 4; ++nt)
      acc[mt][nt] = MFMA16(aA[mt], bB[nt], acc[mt][nt]);
  __builtin_amdgcn_s_setprio(0);
  if constexpr (G2 >= 0) vmcnt_gate<G2>();
  BARRIER;

  // ---- block3: R0' = aA+bA [nbuf] (NEXT); S3 = EARLY(tau+2 -> buf);
  //      LGKM(6|0) drains R3; M3 = aB*bB; G3 gate; bar
  if constexpr (NEXT) {
    #pragma unroll
    for (int t = 0; t < 2; ++t) {
      int ra = wm * 64 + t * 16 + lo;
      aA[t] = *(const bf16x8*)(An + (size_t)ra * 64 + ((hi ^ (ra & 7)) << 3));
    }
    #pragma unroll
    for (int t = 0; t < 4; ++t) {
      int rb = wn * 64 + t * 16 + lo;
      bA[t] = *(const bf16x8*)(Bn + (size_t)rb * 64 + ((hi ^ (rb & 7)) << 3));
    }
  }
  if constexpr (EARLY) {
    const __bf16* Ap2 = Apan + (size_t)(tau + 2) * 64;
    const __bf16* Bp2 = Bpan + (size_t)(tau + 2) * 64;
    stage_q<false>(Ab, 0,  Ap2, K, 0, w, l);      // A q0
    stage_q<false>(Ab, 64, Ap2, K, 0, w, l);      // A q2
    stage_q<BMAP>(Bb, 0,  Bp2, K, boff, w, l);    // B q0
    stage_q<BMAP>(Bb, 32, Bp2, K, boff, w, l);    // B q1
    stage_q<BMAP>(Bb, 64, Bp2, K, boff, w, l);    // B q2
    stage_q<BMAP>(Bb, 96, Bp2, K, boff, w, l);    // B q3
  }
  if constexpr (NEXT) LGKM(6); else LGKM(0);
  __builtin_amdgcn_s_setprio(1);
  #pragma unroll
  for (int mt = 0; mt < 2; ++mt)
    #pragma unroll
    for (int nt = 0; nt < 4; ++nt)
      acc[2 + mt][nt] = MFMA16(aB[mt], bB[nt], acc[2 + mt][nt]);
  __builtin_amdgcn_s_setprio(0);
  if constexpr (G3 >= 0) vmcnt_gate<G3>();
  BARRIER;
}

template <typename CT, int MODE>
__global__ __launch_bounds__(256, 2) void gemm128_kernel(const __bf16* __restrict__ A,
                                                         const __bf16* __restrict__ Bt,
                                                         CT* __restrict__ C, int M, int N, int K,
                                                         const float* __restrict__ cosT,
                                                         const float* __restrict__ sinT,
                                                         int Hh) {
  extern __shared__ __bf16 smem[];
  constexpr bool BMAP = (MODE == 1);

  // XCD-bijective block swizzle (all grids have nwg % 8 == 0)
  const int gx = gridDim.x;
  const int nwg = gx * gridDim.y;
  const int wg = blockIdx.y * gx + blockIdx.x;
  const int qq = nwg >> 3;
  const int id2 = (wg & 7) * qq + (wg >> 3);
  const int m0 = (id2 / gx) * 128, n0 = (id2 % gx) * 128;

  const int tid = threadIdx.x;
  const int l = tid & 63, w = tid >> 6;
  const int lo = l & 15, hi = l >> 4;
  const int wm = w >> 1, wn = w & 1;

  const __bf16* Apan = A + (size_t)m0 * K;
  const int nb = BMAP ? (n0 & ~255) : n0;
  const int boff = BMAP ? (n0 & 255) : 0;
  const __bf16* Bpan = Bt + (size_t)nb * K;

  f32x4 acc[4][4] = {};
  bf16x8 aA[2], aB[2], bA[4], bB[4];

  // prologue: tile0 full (A q0,q2 | B q0..3 | A q1,q3), tile1 EARLY(6) then LATE(2);
  // vmcnt(8) = tile0 landed (per-wave) BEFORE barrier -> cross-wave visible after.
  stage_q<false>(smem,         0,  Apan, K, 0, w, l);
  stage_q<false>(smem,         64, Apan, K, 0, w, l);
  stage_q<BMAP>(smem + 8192,   0,  Bpan, K, boff, w, l);
  stage_q<BMAP>(smem + 8192,   32, Bpan, K, boff, w, l);
  stage_q<BMAP>(smem + 8192,   64, Bpan, K, boff, w, l);
  stage_q<BMAP>(smem + 8192,   96, Bpan, K, boff, w, l);
  stage_q<false>(smem,         32, Apan, K, 0, w, l);
  stage_q<false>(smem,         96, Apan, K, 0, w, l);
  stage_q<false>(smem + 16384, 0,  Apan + 64, K, 0, w, l);
  stage_q<false>(smem + 16384, 64, Apan + 64, K, 0, w, l);
  stage_q<BMAP>(smem + 24576,  0,  Bpan + 64, K, boff, w, l);
  stage_q<BMAP>(smem + 24576,  32, Bpan + 64, K, boff, w, l);
  stage_q<BMAP>(smem + 24576,  64, Bpan + 64, K, boff, w, l);
  stage_q<BMAP>(smem + 24576,  96, Bpan + 64, K, boff, w, l);
  stage_q<false>(smem + 16384, 32, Apan + 64, K, 0, w, l);
  stage_q<false>(smem + 16384, 96, Apan + 64, K, 0, w, l);
  vmcnt_gate<8>();
  BARRIER;

  // R0 of tile0: aA(h0,k0) + bA(k0)
  #pragma unroll
  for (int t = 0; t < 2; ++t) {
    int ra = wm * 64 + t * 16 + lo;
    aA[t] = *(const bf16x8*)(smem + (size_t)ra * 64 + ((hi ^ (ra & 7)) << 3));
  }
  #pragma unroll
  for (int t = 0; t < 4; ++t) {
    int rb = wn * 64 + t * 16 + lo;
    bA[t] = *(const bf16x8*)(smem + 8192 + (size_t)rb * 64 + ((hi ^ (rb & 7)) << 3));
  }

  const int T = K >> 6;
  tile_body<false, true,  true,  2,  6, BMAP>(smem, Apan, Bpan, K, boff, 0,     wm, wn, lo, hi, w, l, aA, aB, bA, bB, acc);
  for (int tau = 1; tau < T - 2; ++tau)
    tile_body<true, true,  true,  2,  6, BMAP>(smem, Apan, Bpan, K, boff, tau,   wm, wn, lo, hi, w, l, aA, aB, bA, bB, acc);
  tile_body<true,  false, true,  2,  0, BMAP>(smem, Apan, Bpan, K, boff, T - 2, wm, wn, lo, hi, w, l, aA, aB, bA, bB, acc);
  tile_body<false, false, false, -1, -1, BMAP>(smem, Apan, Bpan, K, boff, T - 1, wm, wn, lo, hi, w, l, aA, aB, bA, bB, acc);

  if constexpr (MODE == 0) {
    #pragma unroll
    for (int mt = 0; mt < 4; ++mt)
      #pragma unroll
      for (int nt = 0; nt < 4; ++nt) {
        int col = n0 + wn * 64 + nt * 16 + lo;
        #pragma unroll
        for (int r = 0; r < 4; ++r) {
          int row = m0 + wm * 64 + mt * 16 + 4 * hi + r;
          C[(size_t)row * N + col] = (CT)acc[mt][nt][r];
        }
      }
  } else if constexpr (MODE == 2) {
    // V: store to (b, kv, s, d); 128-col block = half a KV head
    const int kv = n0 >> 8;
    const int colb = n0 & 255;
    #pragma unroll
    for (int mt = 0; mt < 4; ++mt)
      #pragma unroll
      for (int nt = 0; nt < 4; ++nt) {
        int col = colb + wn * 64 + nt * 16 + lo;
        #pragma unroll
        for (int r = 0; r < 4; ++r) {
          int row = m0 + wm * 64 + mt * 16 + 4 * hi + r;
          int bb = row >> 12, sdx = row & 4095;
          C[(((size_t)(bb * Hh + kv)) * 4096 + sdx) * 256 + col] = (CT)acc[mt][nt][r];
        }
      }
  } else {
    // MODE 1: fused RoPE; pair (nt, nt+1) = (d, d+128), d = ((boff>>5)+2wn+(nt>>1))*16+lo
    const int hq = n0 >> 8;
    #pragma unroll
    for (int mt = 0; mt < 4; ++mt)
      #pragma unroll
      for (int ntp = 0; ntp < 4; ntp += 2) {
        int d = ((boff >> 5) + 2 * wn + (ntp >> 1)) * 16 + lo;
        #pragma unroll
        for (int r = 0; r < 4; ++r) {
          int row = m0 + wm * 64 + mt * 16 + 4 * hi + r;
          int bb = row >> 12, sdx = row & 4095;
          float cc = cosT[(size_t)sdx * 128 + d];
          float ss = sinT[(size_t)sdx * 128 + d];
          float x1 = acc[mt][ntp][r], x2 = acc[mt][ntp + 1][r];
          size_t base = (((size_t)(bb * Hh + hq)) * 4096 + sdx) * 256;
          C[base + d]       = (CT)(x1 * cc - x2 * ss);
          C[base + d + 128] = (CT)(x1 * ss + x2 * cc);
        }
      }
  }
}

// ---------------- feature map ----------------
__global__ __launch_bounds__(256) void fm_kernel(const __bf16* __restrict__ rope,
                                                 const float* __restrict__ fm,
                                                 __bf16* __restrict__ out, int srcH, float scale) {
  __shared__ __bf16 fmT[64][256];  // [f][d] swizzled: group' = (d>>3) ^ (f&7)
  int bh = blockIdx.y;
  int h = bh & 15, b = bh >> 4;
  int s0 = blockIdx.x * 128;
  int tid = threadIdx.x, lane = tid & 63, wid = tid >> 6, hi = lane >> 4, lo = lane & 15;

  const float* fmh = fm + (size_t)h * 256 * 64;
  for (int i = tid; i < 256 * 64; i += 256) {
    int d = i >> 6, f = i & 63;
    fmT[f][(((d >> 3) ^ (f & 7)) << 3) | (d & 7)] = (__bf16)fmh[i];
  }
  __syncthreads();

  int srch = (srcH == 16) ? h : (h >> 1);
  const __bf16* abase = rope + ((size_t)(b * srcH + srch) * 4096 + s0 + 32 * wid) * 256;
  f32x4 acc[2][4] = {};
  for (int kk = 0; kk < 256; kk += 32) {
    bf16x8 a[2], bf[4];
    #pragma unroll
    for (int mt = 0; mt < 2; ++mt)
      a[mt] = *(const bf16x8*)(abase + (size_t)(16 * mt + lo) * 256 + kk + 8 * hi);
    const int G = (kk >> 3) + hi;
    #pragma unroll
    for (int nt = 0; nt < 4; ++nt) {
      int f = 16 * nt + lo;
      bf[nt] = *(const bf16x8*)&fmT[f][(G ^ (f & 7)) << 3];
    }
    #pragma unroll
    for (int mt = 0; mt < 2; ++mt)
      #pragma unroll
      for (int nt = 0; nt < 4; ++nt)
        acc[mt][nt] = MFMA16(a[mt], bf[nt], acc[mt][nt]);
  }

  size_t obase = ((size_t)(b * 16 + h) * 4096 + s0 + 32 * wid);
  #pragma unroll
  for (int mt = 0; mt < 2; ++mt) {
    #pragma unroll
    for (int r = 0; r < 4; ++r) {
      float z0 = acc[mt][0][r], z1 = acc[mt][1][r], z2 = acc[mt][2][r], z3 = acc[mt][3][r];
      float mx = fmaxf(fmaxf(z0, z1), fmaxf(z2, z3));
      float mn = fminf(fminf(z0, z1), fminf(z2, z3));
      #pragma unroll
      for (int off = 1; off < 16; off <<= 1) {
        mx = fmaxf(mx, __shfl_xor(mx, off));
        mn = fminf(mn, __shfl_xor(mn, off));
      }
      float ep0 = __expf(z0 - mx), ep1 = __expf(z1 - mx), ep2 = __expf(z2 - mx), ep3 = __expf(z3 - mx);
      float en0 = __expf(mn - z0), en1 = __expf(mn - z1), en2 = __expf(mn - z2), en3 = __expf(mn - z3);
      float sp = ep0 + ep1 + ep2 + ep3, sn = en0 + en1 + en2 + en3;
      #pragma unroll
      for (int off = 1; off < 16; off <<= 1) {
        sp += __shfl_xor(sp, off);
        sn += __shfl_xor(sn, off);
      }
      float rp = scale / sp, rn = scale / sn;
      int row = 16 * mt + 4 * hi + r;
      __bf16* op = out + (obase + row) * 128;
      op[0  + lo] = (__bf16)(ep0 * rp);  op[16 + lo] = (__bf16)(ep1 * rp);
      op[32 + lo] = (__bf16)(ep2 * rp);  op[48 + lo] = (__bf16)(ep3 * rp);
      op[64 + lo] = (__bf16)(en0 * rn);  op[80 + lo] = (__bf16)(en1 * rn);
      op[96 + lo] = (__bf16)(en2 * rn);  op[112 + lo] = (__bf16)(en3 * rn);
    }
  }
}

// ---------------- chunked linear attention ----------------
__global__ __launch_bounds__(256) void attn_kernel(const __bf16* __restrict__ qf,
                                                   const __bf16* __restrict__ kf,
                                                   const __bf16* __restrict__ vp,
                                                   __bf16* __restrict__ o) {
  __shared__ __bf16 k_s[64][128];
  __shared__ __bf16 vT_s[32][64];
  __shared__ __bf16 sc_s[64][64];
  __shared__ __bf16 STb[32][128];

  int bid = blockIdx.x;
  int dvb = bid & 7, h = (bid >> 3) & 15, b = bid >> 7;
  int dv0 = dvb * 32;
  int tid = threadIdx.x, lane = tid & 63, wid = tid >> 6, hi = lane >> 4, lo = lane & 15;

  const __bf16* qh = qf + ((size_t)(b * 16 + h)) * 4096 * 128;
  const __bf16* kh = kf + ((size_t)(b * 16 + h)) * 4096 * 128;
  const __bf16* vh = vp + ((size_t)(b * 8 + (h >> 1))) * 4096 * 256 + dv0;
  __bf16* oh = o + ((size_t)b * 4096) * 4096 + h * 256 + dv0;

  {
    unsigned int* z = (unsigned int*)&STb[0][0];
    for (int i = tid; i < 2048; i += 256) z[i] = 0u;
  }
  f32x4 st[2][2] = {};

  for (int n = 0; n < 64; ++n) {
    int s0 = n * 64;
    #pragma unroll
    for (int i = 0; i < 4; ++i) {
      int rb = (wid * 4 + i) * 4;
      int r = rb + (lane >> 4);
      int Glog = (lane & 15) ^ (r & 7);
      async_copy16(&k_s[rb][0], kh + (size_t)(s0 + r) * 128 + Glog * 8);
    }
    {
      int c = tid >> 2, d8 = (tid & 3) * 8;
      bf16x8 vv = *(const bf16x8*)(vh + (size_t)(s0 + c) * 256 + d8);
      #pragma unroll
      for (int j = 0; j < 8; ++j) {
        int dv = d8 + j;
        vT_s[dv][(((c >> 3) ^ (dv & 7)) << 3) | (c & 7)] = vv[j];
      }
    }
    __syncthreads();

    bf16x8 aq[4];
    #pragma unroll
    for (int kq = 0; kq < 4; ++kq)
      aq[kq] = *(const bf16x8*)(qh + (size_t)(s0 + 16 * wid + lo) * 128 + 32 * kq + 8 * hi);

    f32x4 acc_o[2] = {}, sacc[4] = {};
    #pragma unroll
    for (int nt = 0; nt < 2; ++nt)
      #pragma unroll
      for (int kq = 0; kq < 4; ++kq) {
        int rr = 16 * nt + lo, G = 4 * kq + hi;
        bf16x8 bf = *(const bf16x8*)&STb[rr][(G ^ (rr & 7)) << 3];
        acc_o[nt] = MFMA16(aq[kq], bf, acc_o[nt]);
      }
    #pragma unroll
    for (int nt = 0; nt < 4; ++nt)
      #pragma unroll
      for (int kq = 0; kq < 4; ++kq) {
        int rr = 16 * nt + lo, G = 4 * kq + hi;
        bf16x8 bf = *(const bf16x8*)&k_s[rr][(G ^ (rr & 7)) << 3];
        sacc[nt] = MFMA16(aq[kq], bf, sacc[nt]);
      }
    #pragma unroll
    for (int nt = 0; nt < 4; ++nt)
      #pragma unroll
      for (int r = 0; r < 4; ++r) {
        int c = 16 * wid + 4 * hi + r;
        int cp = 16 * nt + lo;
        float v = (cp <= c) ? sacc[nt][r] : 0.0f;
        sc_s[c][(((cp >> 3) ^ (c & 7)) << 3) | (cp & 7)] = (__bf16)v;
      }
    asm volatile("" ::: "memory");
    #pragma unroll
    for (int nt = 0; nt < 2; ++nt)
      #pragma unroll
      for (int kq = 0; kq < 2; ++kq) {
        int rA = 16 * wid + lo, GA = 4 * kq + hi;
        bf16x8 af = *(const bf16x8*)&sc_s[rA][(GA ^ (rA & 7)) << 3];
        int rB = 16 * nt + lo;
        bf16x8 bf = *(const bf16x8*)&vT_s[rB][(GA ^ (rB & 7)) << 3];
        acc_o[nt] = MFMA16(af, bf, acc_o[nt]);
      }
    #pragma unroll
    for (int nt = 0; nt < 2; ++nt)
      #pragma unroll
      for (int r = 0; r < 4; ++r) {
        int c = 16 * wid + 4 * hi + r;
        oh[(size_t)(s0 + c) * 4096 + 16 * nt + lo] = (__bf16)acc_o[nt][r];
      }
    __syncthreads();

    bf16x8 bu[2][2];
    #pragma unroll
    for (int q = 0; q < 2; ++q) {
      int dk = 16 * (2 * wid + q) + lo;
      #pragma unroll
      for (int kq = 0; kq < 2; ++kq) {
        bf16x8 tmp;
        #pragma unroll
        for (int j = 0; j < 8; ++j) {
          int c = 32 * kq + 8 * hi + j;
          tmp[j] = k_s[c][(((dk >> 3) ^ (c & 7)) << 3) | (dk & 7)];
        }
        bu[q][kq] = tmp;
      }
    }
    #pragma unroll
    for (int mt = 0; mt < 2; ++mt)
      #pragma unroll
      for (int kq = 0; kq < 2; ++kq) {
        int rA = 16 * mt + lo, GA = 4 * kq + hi;
        bf16x8 av = *(const bf16x8*)&vT_s[rA][(GA ^ (rA & 7)) << 3];
        #pragma unroll
        for (int q = 0; q < 2; ++q)
          st[mt][q] = MFMA16(av, bu[q][kq], st[mt][q]);
      }
    #pragma unroll
    for (int mt = 0; mt < 2; ++mt)
      #pragma unroll
      for (int q = 0; q < 2; ++q) {
        int dk = 16 * (2 * wid + q) + lo;
        #pragma unroll
        for (int r = 0; r < 4; ++r) {
          int dvr = 16 * mt + 4 * hi + r;
          STb[dvr][(((dk >> 3) ^ (dvr & 7)) << 3) | (dk & 7)] = (__bf16)st[mt][q][r];
        }
      }
    __syncthreads();
  }
}

// ---------------- launch ----------------
extern "C" void kernel_launch(void* const* d_in, const int* in_sizes, int n_in,
                              void* d_out, int out_size, void* d_ws, size_t ws_size,
                              hipStream_t stream) {
  (void)in_sizes; (void)n_in; (void)out_size; (void)ws_size;
  const float* hs   = (const float*)d_in[0];
  const float* cosT = (const float*)d_in[1];
  const float* sinT = (const float*)d_in[2];
  const float* Wq   = (const float*)d_in[3];
  const float* Wk   = (const float*)d_in[4];
  const float* Wv   = (const float*)d_in[5];
  const float* Wo   = (const float*)d_in[6];
  const float* fmq  = (const float*)d_in[7];
  const float* fmk  = (const float*)d_in[8];
  float* out = (float*)d_out;
  char* ws = (char*)d_ws;

  hipFuncSetAttribute((const void*)gemm128_kernel<float, 0>,
                      hipFuncAttributeMaxDynamicSharedMemorySize, 65536);
  hipFuncSetAttribute((const void*)gemm128_kernel<__bf16, 1>,
                      hipFuncAttributeMaxDynamicSharedMemorySize, 65536);
  hipFuncSetAttribute((const void*)gemm128_kernel<__bf16, 2>,
                      hipFuncAttributeMaxDynamicSharedMemorySize, 65536);

  const size_t MB = 1024ull * 1024ull;
  __bf16* Xb   = (__bf16*)(ws + 0);
  __bf16* qfb  = (__bf16*)(ws + 0);
  __bf16* kfb  = (__bf16*)(ws + 34 * MB);
  __bf16* Wqt  = (__bf16*)(ws + 70 * MB);
  __bf16* ob   = (__bf16*)(ws + 70 * MB);
  __bf16* Wkt  = (__bf16*)(ws + 104 * MB);
  __bf16* Wvt  = (__bf16*)(ws + 119 * MB);
  __bf16* Wot  = (__bf16*)(ws + 140 * MB);
  __bf16* ropq = (__bf16*)(ws + 170 * MB);
  __bf16* ropk = (__bf16*)(ws + 238 * MB);
  __bf16* vpb  = (__bf16*)(ws + 272 * MB);

  convert_kernel<<<28672, 256, 0, stream>>>(hs, Xb, (size_t)8192 * 3584 / 4);
  transpose_kernel<<<dim3(128, 112), 256, 0, stream>>>(Wq, Wqt, 3584, 4096);
  transpose_kernel<<<dim3(64, 112),  256, 0, stream>>>(Wk, Wkt, 3584, 2048);
  transpose_kernel<<<dim3(64, 112),  256, 0, stream>>>(Wv, Wvt, 3584, 2048);
  transpose_kernel<<<dim3(112, 128), 256, 0, stream>>>(Wo, Wot, 4096, 3584);

  gemm128_kernel<__bf16, 1><<<dim3(32, 64), 256, 65536, stream>>>(
      Xb, Wqt, ropq, 8192, 4096, 3584, cosT, sinT, 16);
  gemm128_kernel<__bf16, 1><<<dim3(16, 64), 256, 65536, stream>>>(
      Xb, Wkt, ropk, 8192, 2048, 3584, cosT, sinT, 8);
  gemm128_kernel<__bf16, 2><<<dim3(16, 64), 256, 65536, stream>>>(
      Xb, Wvt, vpb, 8192, 2048, 3584, nullptr, nullptr, 8);

  fm_kernel<<<dim3(32, 32), 256, 0, stream>>>(ropq, fmq, qfb, 16, 0.08838834764831845f);
  fm_kernel<<<dim3(32, 32), 256, 0, stream>>>(ropk, fmk, kfb, 8, 1.0f);

  attn_kernel<<<256, 256, 0, stream>>>(qfb, kfb, vpb, ob);

  gemm128_kernel<float, 0><<<dim3(28, 64), 256, 65536, stream>>>(
      ob, Wot, out, 8192, 3584, 4096, nullptr, nullptr, 0);
}

// Round 7
// 944.290 us; speedup vs baseline: 1.1672x; 1.1672x over previous
//
#include <hip/hip_runtime.h>

// ---------------- types / helpers ----------------
typedef float  f32x4  __attribute__((ext_vector_type(4)));
typedef __bf16 bf16x4 __attribute__((ext_vector_type(4)));
typedef __bf16 bf16x8 __attribute__((ext_vector_type(8)));

#define MFMA16(a,b,c) __builtin_amdgcn_mfma_f32_16x16x32_bf16((a),(b),(c),0,0,0)

__device__ __forceinline__ void async_copy16(void* lds, const void* gmem) {
  __builtin_amdgcn_global_load_lds(
      (const __attribute__((address_space(1))) void*)gmem,
      (__attribute__((address_space(3))) void*)lds, 16, 0, 0);
}

template<int N> __device__ __forceinline__ void vmcnt_gate() {
  if constexpr (N == 8) asm volatile("s_waitcnt vmcnt(8)" ::: "memory");
  else if constexpr (N == 6) asm volatile("s_waitcnt vmcnt(6)" ::: "memory");
  else if constexpr (N == 4) asm volatile("s_waitcnt vmcnt(4)" ::: "memory");
  else if constexpr (N == 2) asm volatile("s_waitcnt vmcnt(2)" ::: "memory");
  else if constexpr (N == 0) asm volatile("s_waitcnt vmcnt(0)" ::: "memory");
  __builtin_amdgcn_sched_barrier(0);
}

// counted lgkm wait: drains all ds_reads OLDER than the N just issued (rule #18 fences)
#define LGKM(N) do { __builtin_amdgcn_sched_barrier(0); \
                     asm volatile("s_waitcnt lgkmcnt(" #N ")" ::: "memory"); \
                     __builtin_amdgcn_sched_barrier(0); } while (0)

#define BARRIER do { __builtin_amdgcn_sched_barrier(0); \
                     __builtin_amdgcn_s_barrier(); \
                     __builtin_amdgcn_sched_barrier(0); } while (0)

// ---------------- convert f32 -> bf16 (vectorized x4) ----------------
__global__ __launch_bounds__(256) void convert_kernel(const float* __restrict__ in,
                                                      __bf16* __restrict__ out, size_t n4) {
  size_t i = (size_t)blockIdx.x * 256 + threadIdx.x;
  if (i >= n4) return;
  f32x4 v = *(const f32x4*)(in + i * 4);
  bf16x4 o;
  #pragma unroll
  for (int j = 0; j < 4; ++j) o[j] = (__bf16)v[j];
  *(bf16x4*)(out + i * 4) = o;
}

// ---------------- transpose + convert: in f32 (R,C) -> out bf16 (C,R) ----------------
__global__ __launch_bounds__(256) void transpose_kernel(const float* __restrict__ in,
                                                        __bf16* __restrict__ out, int R, int C) {
  __shared__ float tile[32][33];
  int bx = blockIdx.x, by = blockIdx.y;
  int tx = threadIdx.x & 31, ty0 = threadIdx.x >> 5;
  #pragma unroll
  for (int i = 0; i < 4; ++i) {
    int r = by * 32 + ty0 + i * 8;
    tile[ty0 + i * 8][tx] = in[(size_t)r * C + bx * 32 + tx];
  }
  __syncthreads();
  #pragma unroll
  for (int i = 0; i < 4; ++i) {
    int c = bx * 32 + ty0 + i * 8;
    out[(size_t)c * R + by * 32 + tx] = (__bf16)tile[tx][ty0 + i * 8];
  }
}

// ---------------- 256x256 pipelined bf16 GEMM (R5 = best measured, REVERTED) ---------
// R6's 128^2/2-blocks-per-CU experiment REGRESSED: FETCH 264->918MB (A-panel re-reads
// miss L2 with half-size tiles), HBM 44% peak, MfmaUtil 37%. 256^2 is the minimum
// tile for L2-viable reuse at these shapes. GEMM frozen at the R3/R5 schedule.
// K-loop (978us, race-proven): see R3 comments. MODE epilogues (R5): 0=plain,
// 1=RoPE fused (B-panel colmap permute -> intra-thread butterfly), 2=V permuted store.

template<bool REMAP>
__device__ __forceinline__ void stage_q(__bf16* region, int qrow, const __bf16* src,
                                        int K, int w, int l) {
  int s = qrow + w * 8 + (l >> 3);
  int gr = REMAP ? (((s >> 5) << 4) | (s & 15) | (((s >> 4) & 1) << 7)) : s;
  async_copy16(region + (size_t)(qrow + w * 8) * 64,
               src + (size_t)gr * K + (((l & 7) ^ (s & 7)) << 3));
}

template<bool LATE, bool EARLY, bool NEXT, int G2, int G3, bool BMAP>
__device__ __forceinline__ void tile_body(__bf16* smem,
                                          const __bf16* Apan, const __bf16* Bpan,
                                          int K, int tau, int wm, int wn,
                                          int lo, int hi, int w, int l,
                                          bf16x8 (&aA)[4], bf16x8 (&aB)[4],
                                          bf16x8 (&bA)[4], bf16x8 (&bB)[4],
                                          f32x4 (&acc)[8][4]) {
  const int buf = tau & 1;
  __bf16* Ab = smem + buf * 32768;
  __bf16* Bb = Ab + 16384;
  __bf16* An = smem + (buf ^ 1) * 32768;
  __bf16* Bn = An + 16384;

  // ---- block0: R1 = aB <- a(h1,k0)[buf]; S0 = LATE; lgkm(4) drains R0; M0 = aA*bA
  #pragma unroll
  for (int t = 0; t < 4; ++t) {
    int ra = wm * 128 + 64 + t * 16 + lo;
    aB[t] = *(const bf16x8*)(Ab + (size_t)ra * 64 + ((hi ^ (ra & 7)) << 3));
  }
  if constexpr (LATE) {
    const __bf16* Ap1 = Apan + (size_t)(tau + 1) * 64;
    stage_q<false>(An, 64,  Ap1, K, w, l);   // A q1
    stage_q<false>(An, 192, Ap1, K, w, l);   // A q3
  }
  LGKM(4);
  __builtin_amdgcn_s_setprio(1);
  #pragma unroll
  for (int mt = 0; mt < 4; ++mt)
    #pragma unroll
    for (int nt = 0; nt < 4; ++nt)
      acc[mt][nt] = MFMA16(aA[mt], bA[nt], acc[mt][nt]);
  __builtin_amdgcn_s_setprio(0);
  BARRIER;

  // ---- block1: R2 = aA <- a(h0,k1), bB <- b(k1) [buf]; lgkm(8) drains R1; M1 = aB*bA
  #pragma unroll
  for (int t = 0; t < 4; ++t) {
    int ra = wm * 128 + t * 16 + lo;
    aA[t] = *(const bf16x8*)(Ab + (size_t)ra * 64 + (((4 + hi) ^ (ra & 7)) << 3));
  }
  #pragma unroll
  for (int t = 0; t < 4; ++t) {
    int rb = wn * 64 + t * 16 + lo;
    bB[t] = *(const bf16x8*)(Bb + (size_t)rb * 64 + (((4 + hi) ^ (rb & 7)) << 3));
  }
  LGKM(8);
  __builtin_amdgcn_s_setprio(1);
  #pragma unroll
  for (int mt = 0; mt < 4; ++mt)
    #pragma unroll
    for (int nt = 0; nt < 4; ++nt)
      acc[4 + mt][nt] = MFMA16(aB[mt], bA[nt], acc[4 + mt][nt]);
  __builtin_amdgcn_s_setprio(0);
  BARRIER;

  // ---- block2: R3 = aB <- a(h1,k1)[buf]; lgkm(4) drains R2; M2 = aA*bB;
  //      G2 gate BEFORE bar2 (cross-wave: EARLY(tau+1) landed for everyone)
  #pragma unroll
  for (int t = 0; t < 4; ++t) {
    int ra = wm * 128 + 64 + t * 16 + lo;
    aB[t] = *(const bf16x8*)(Ab + (size_t)ra * 64 + (((4 + hi) ^ (ra & 7)) << 3));
  }
  LGKM(4);
  __builtin_amdgcn_s_setprio(1);
  #pragma unroll
  for (int mt = 0; mt < 4; ++mt)
    #pragma unroll
    for (int nt = 0; nt < 4; ++nt)
      acc[mt][nt] = MFMA16(aA[mt], bB[nt], acc[mt][nt]);
  __builtin_amdgcn_s_setprio(0);
  if constexpr (G2 >= 0) vmcnt_gate<G2>();
  BARRIER;

  // ---- block3: R0' = aA <- a(h0,k0), bA <- b(k0) [nbuf] (NEXT); S3 = EARLY(tau+2 -> buf);
  //      lgkm(8|0) drains R3; M3 = aB*bB; G3 gate BEFORE bar3 (LATE landed for everyone)
  if constexpr (NEXT) {
    #pragma unroll
    for (int t = 0; t < 4; ++t) {
      int ra = wm * 128 + t * 16 + lo;
      aA[t] = *(const bf16x8*)(An + (size_t)ra * 64 + ((hi ^ (ra & 7)) << 3));
    }
    #pragma unroll
    for (int t = 0; t < 4; ++t) {
      int rb = wn * 64 + t * 16 + lo;
      bA[t] = *(const bf16x8*)(Bn + (size_t)rb * 64 + ((hi ^ (rb & 7)) << 3));
    }
  }
  if constexpr (EARLY) {
    const __bf16* Ap2 = Apan + (size_t)(tau + 2) * 64;
    const __bf16* Bp2 = Bpan + (size_t)(tau + 2) * 64;
    stage_q<false>(Ab, 0,   Ap2, K, w, l);   // A q0
    stage_q<false>(Ab, 128, Ap2, K, w, l);   // A q2
    stage_q<BMAP>(Bb, 0,   Bp2, K, w, l);    // B q0
    stage_q<BMAP>(Bb, 64,  Bp2, K, w, l);    // B q1
    stage_q<BMAP>(Bb, 128, Bp2, K, w, l);    // B q2
    stage_q<BMAP>(Bb, 192, Bp2, K, w, l);    // B q3
  }
  if constexpr (NEXT) LGKM(8); else LGKM(0);
  __builtin_amdgcn_s_setprio(1);
  #pragma unroll
  for (int mt = 0; mt < 4; ++mt)
    #pragma unroll
    for (int nt = 0; nt < 4; ++nt)
      acc[4 + mt][nt] = MFMA16(aB[mt], bB[nt], acc[4 + mt][nt]);
  __builtin_amdgcn_s_setprio(0);
  if constexpr (G3 >= 0) vmcnt_gate<G3>();
  BARRIER;
}

template <typename CT, int MODE>
__global__ __launch_bounds__(512, 2) void gemm256_kernel(const __bf16* __restrict__ A,
                                                         const __bf16* __restrict__ Bt,
                                                         CT* __restrict__ C, int M, int N, int K,
                                                         const float* __restrict__ cosT,
                                                         const float* __restrict__ sinT,
                                                         int Hh) {
  extern __shared__ __bf16 smem[];
  constexpr bool BMAP = (MODE == 1);

  // XCD-bijective block swizzle (all grids have nwg % 8 == 0)
  const int gx = gridDim.x;
  const int nwg = gx * gridDim.y;
  const int wg = blockIdx.y * gx + blockIdx.x;
  const int qq = nwg >> 3;
  const int id2 = (wg & 7) * qq + (wg >> 3);
  const int m0 = (id2 / gx) * 256, n0 = (id2 % gx) * 256;

  const int tid = threadIdx.x;
  const int l = tid & 63, w = tid >> 6;
  const int lo = l & 15, hi = l >> 4;
  const int wm = w >> 2, wn = w & 3;

  const __bf16* Apan = A + (size_t)m0 * K;
  const __bf16* Bpan = Bt + (size_t)n0 * K;

  f32x4 acc[8][4] = {};
  bf16x8 aA[4], aB[4], bA[4], bB[4];

  // prologue: stage tile0 (8 quanta) + tile1 (EARLY order first, LATE last);
  // vmcnt(8) = tile0 landed (per-wave) BEFORE barrier -> cross-wave visible after.
  stage_q<false>(smem,          0,   Apan, K, w, l);
  stage_q<false>(smem,          128, Apan, K, w, l);
  stage_q<BMAP>(smem + 16384,  0,   Bpan, K, w, l);
  stage_q<BMAP>(smem + 16384,  64,  Bpan, K, w, l);
  stage_q<BMAP>(smem + 16384,  128, Bpan, K, w, l);
  stage_q<BMAP>(smem + 16384,  192, Bpan, K, w, l);
  stage_q<false>(smem,          64,  Apan, K, w, l);
  stage_q<false>(smem,          192, Apan, K, w, l);
  stage_q<false>(smem + 32768,  0,   Apan + 64, K, w, l);
  stage_q<false>(smem + 32768,  128, Apan + 64, K, w, l);
  stage_q<BMAP>(smem + 49152,  0,   Bpan + 64, K, w, l);
  stage_q<BMAP>(smem + 49152,  64,  Bpan + 64, K, w, l);
  stage_q<BMAP>(smem + 49152,  128, Bpan + 64, K, w, l);
  stage_q<BMAP>(smem + 49152,  192, Bpan + 64, K, w, l);
  stage_q<false>(smem + 32768,  64,  Apan + 64, K, w, l);
  stage_q<false>(smem + 32768,  192, Apan + 64, K, w, l);
  vmcnt_gate<8>();
  BARRIER;

  #pragma unroll
  for (int t = 0; t < 4; ++t) {
    int ra = wm * 128 + t * 16 + lo;
    aA[t] = *(const bf16x8*)(smem + (size_t)ra * 64 + ((hi ^ (ra & 7)) << 3));
  }
  #pragma unroll
  for (int t = 0; t < 4; ++t) {
    int rb = wn * 64 + t * 16 + lo;
    bA[t] = *(const bf16x8*)(smem + 16384 + (size_t)rb * 64 + ((hi ^ (rb & 7)) << 3));
  }

  const int T = K >> 6;
  tile_body<false, true,  true,  2,  6, BMAP>(smem, Apan, Bpan, K, 0,     wm, wn, lo, hi, w, l, aA, aB, bA, bB, acc);
  for (int tau = 1; tau < T - 2; ++tau)
    tile_body<true, true,  true,  2,  6, BMAP>(smem, Apan, Bpan, K, tau,   wm, wn, lo, hi, w, l, aA, aB, bA, bB, acc);
  tile_body<true,  false, true,  2,  0, BMAP>(smem, Apan, Bpan, K, T - 2, wm, wn, lo, hi, w, l, aA, aB, bA, bB, acc);
  tile_body<false, false, false, -1, -1, BMAP>(smem, Apan, Bpan, K, T - 1, wm, wn, lo, hi, w, l, aA, aB, bA, bB, acc);

  if constexpr (MODE == 0) {
    // plain row-major C
    #pragma unroll
    for (int mt = 0; mt < 8; ++mt)
      #pragma unroll
      for (int nt = 0; nt < 4; ++nt) {
        int col = n0 + wn * 64 + nt * 16 + lo;
        #pragma unroll
        for (int r = 0; r < 4; ++r) {
          int row = m0 + wm * 128 + mt * 16 + 4 * hi + r;
          C[(size_t)row * N + col] = (CT)acc[mt][nt][r];
        }
      }
  } else if constexpr (MODE == 2) {
    // V: store to (b, kv, s, d); n-block == one KV head
    const int kv = n0 >> 8;
    #pragma unroll
    for (int mt = 0; mt < 8; ++mt)
      #pragma unroll
      for (int nt = 0; nt < 4; ++nt) {
        int col = wn * 64 + nt * 16 + lo;
        #pragma unroll
        for (int r = 0; r < 4; ++r) {
          int row = m0 + wm * 128 + mt * 16 + 4 * hi + r;
          int bb = row >> 12, sdx = row & 4095;
          C[(((size_t)(bb * Hh + kv)) * 4096 + sdx) * 256 + col] = (CT)acc[mt][nt][r];
        }
      }
  } else {
    // MODE 1: fused RoPE + store to (b, h, s, d). acc cols are colmap-permuted:
    // pair (nt, nt+1) = (d, d+128) with d = (2*wn + (nt>>1))*16 + lo.
    const int hq = n0 >> 8;
    #pragma unroll
    for (int mt = 0; mt < 8; ++mt)
      #pragma unroll
      for (int ntp = 0; ntp < 4; ntp += 2) {
        int d = (2 * wn + (ntp >> 1)) * 16 + lo;
        #pragma unroll
        for (int r = 0; r < 4; ++r) {
          int row = m0 + wm * 128 + mt * 16 + 4 * hi + r;
          int bb = row >> 12, sdx = row & 4095;
          float cc = cosT[(size_t)sdx * 128 + d];
          float ss = sinT[(size_t)sdx * 128 + d];
          float x1 = acc[mt][ntp][r], x2 = acc[mt][ntp + 1][r];
          size_t base = (((size_t)(bb * Hh + hq)) * 4096 + sdx) * 256;
          C[base + d]       = (CT)(x1 * cc - x2 * ss);
          C[base + d + 128] = (CT)(x1 * ss + x2 * cc);
        }
      }
  }
}

// ---------------- feature map ----------------
__global__ __launch_bounds__(256) void fm_kernel(const __bf16* __restrict__ rope,
                                                 const float* __restrict__ fm,
                                                 __bf16* __restrict__ out, int srcH, float scale) {
  __shared__ __bf16 fmT[64][256];  // [f][d] swizzled: group' = (d>>3) ^ (f&7)
  int bh = blockIdx.y;
  int h = bh & 15, b = bh >> 4;
  int s0 = blockIdx.x * 128;
  int tid = threadIdx.x, lane = tid & 63, wid = tid >> 6, hi = lane >> 4, lo = lane & 15;

  const float* fmh = fm + (size_t)h * 256 * 64;
  for (int i = tid; i < 256 * 64; i += 256) {
    int d = i >> 6, f = i & 63;
    fmT[f][(((d >> 3) ^ (f & 7)) << 3) | (d & 7)] = (__bf16)fmh[i];
  }
  __syncthreads();

  int srch = (srcH == 16) ? h : (h >> 1);
  const __bf16* abase = rope + ((size_t)(b * srcH + srch) * 4096 + s0 + 32 * wid) * 256;
  f32x4 acc[2][4] = {};
  for (int kk = 0; kk < 256; kk += 32) {
    bf16x8 a[2], bf[4];
    #pragma unroll
    for (int mt = 0; mt < 2; ++mt)
      a[mt] = *(const bf16x8*)(abase + (size_t)(16 * mt + lo) * 256 + kk + 8 * hi);
    const int G = (kk >> 3) + hi;
    #pragma unroll
    for (int nt = 0; nt < 4; ++nt) {
      int f = 16 * nt + lo;
      bf[nt] = *(const bf16x8*)&fmT[f][(G ^ (f & 7)) << 3];
    }
    #pragma unroll
    for (int mt = 0; mt < 2; ++mt)
      #pragma unroll
      for (int nt = 0; nt < 4; ++nt)
        acc[mt][nt] = MFMA16(a[mt], bf[nt], acc[mt][nt]);
  }

  size_t obase = ((size_t)(b * 16 + h) * 4096 + s0 + 32 * wid);
  #pragma unroll
  for (int mt = 0; mt < 2; ++mt) {
    #pragma unroll
    for (int r = 0; r < 4; ++r) {
      float z0 = acc[mt][0][r], z1 = acc[mt][1][r], z2 = acc[mt][2][r], z3 = acc[mt][3][r];
      float mx = fmaxf(fmaxf(z0, z1), fmaxf(z2, z3));
      float mn = fminf(fminf(z0, z1), fminf(z2, z3));
      #pragma unroll
      for (int off = 1; off < 16; off <<= 1) {
        mx = fmaxf(mx, __shfl_xor(mx, off));
        mn = fminf(mn, __shfl_xor(mn, off));
      }
      float ep0 = __expf(z0 - mx), ep1 = __expf(z1 - mx), ep2 = __expf(z2 - mx), ep3 = __expf(z3 - mx);
      float en0 = __expf(mn - z0), en1 = __expf(mn - z1), en2 = __expf(mn - z2), en3 = __expf(mn - z3);
      float sp = ep0 + ep1 + ep2 + ep3, sn = en0 + en1 + en2 + en3;
      #pragma unroll
      for (int off = 1; off < 16; off <<= 1) {
        sp += __shfl_xor(sp, off);
        sn += __shfl_xor(sn, off);
      }
      float rp = scale / sp, rn = scale / sn;
      int row = 16 * mt + 4 * hi + r;
      __bf16* op = out + (obase + row) * 128;
      op[0  + lo] = (__bf16)(ep0 * rp);  op[16 + lo] = (__bf16)(ep1 * rp);
      op[32 + lo] = (__bf16)(ep2 * rp);  op[48 + lo] = (__bf16)(ep3 * rp);
      op[64 + lo] = (__bf16)(en0 * rn);  op[80 + lo] = (__bf16)(en1 * rn);
      op[96 + lo] = (__bf16)(en2 * rn);  op[112 + lo] = (__bf16)(en3 * rn);
    }
  }
}

// ---------------- chunked linear attention ----------------
// NEW (R7): XCD-locality block remap. The 8 dv-sibling blocks of one (b,h) read the
// SAME full q/k head-slice (1MB each). Old bid = g*8+dvb put siblings on 8 DIFFERENT
// XCDs (round-robin) -> 8x HBM re-fetch (~540MB). New map keeps bid%8 equal for all
// siblings -> same XCD -> q/k slices are L2-local (1 fetch, 7 hits):
//   bid = 64*(g>>3) + dvb*8 + (g&7)  =>  g = ((bid>>6)<<3)|(bid&7), dvb = (bid>>3)&7.
__global__ __launch_bounds__(256) void attn_kernel(const __bf16* __restrict__ qf,
                                                   const __bf16* __restrict__ kf,
                                                   const __bf16* __restrict__ vp,
                                                   __bf16* __restrict__ o) {
  __shared__ __bf16 k_s[64][128];
  __shared__ __bf16 vT_s[32][64];
  __shared__ __bf16 sc_s[64][64];
  __shared__ __bf16 STb[32][128];

  int bid = blockIdx.x;
  int g   = ((bid >> 6) << 3) | (bid & 7);   // 0..31 = b*16 + h
  int dvb = (bid >> 3) & 7;
  int h = g & 15, b = g >> 4;
  int dv0 = dvb * 32;
  int tid = threadIdx.x, lane = tid & 63, wid = tid >> 6, hi = lane >> 4, lo = lane & 15;

  const __bf16* qh = qf + ((size_t)(b * 16 + h)) * 4096 * 128;
  const __bf16* kh = kf + ((size_t)(b * 16 + h)) * 4096 * 128;
  const __bf16* vh = vp + ((size_t)(b * 8 + (h >> 1))) * 4096 * 256 + dv0;
  __bf16* oh = o + ((size_t)b * 4096) * 4096 + h * 256 + dv0;

  {
    unsigned int* z = (unsigned int*)&STb[0][0];
    for (int i = tid; i < 2048; i += 256) z[i] = 0u;
  }
  f32x4 st[2][2] = {};

  for (int n = 0; n < 64; ++n) {
    int s0 = n * 64;
    #pragma unroll
    for (int i = 0; i < 4; ++i) {
      int rb = (wid * 4 + i) * 4;
      int r = rb + (lane >> 4);
      int Glog = (lane & 15) ^ (r & 7);
      async_copy16(&k_s[rb][0], kh + (size_t)(s0 + r) * 128 + Glog * 8);
    }
    {
      int c = tid >> 2, d8 = (tid & 3) * 8;
      bf16x8 vv = *(const bf16x8*)(vh + (size_t)(s0 + c) * 256 + d8);
      #pragma unroll
      for (int j = 0; j < 8; ++j) {
        int dv = d8 + j;
        vT_s[dv][(((c >> 3) ^ (dv & 7)) << 3) | (c & 7)] = vv[j];
      }
    }
    __syncthreads();

    bf16x8 aq[4];
    #pragma unroll
    for (int kq = 0; kq < 4; ++kq)
      aq[kq] = *(const bf16x8*)(qh + (size_t)(s0 + 16 * wid + lo) * 128 + 32 * kq + 8 * hi);

    f32x4 acc_o[2] = {}, sacc[4] = {};
    #pragma unroll
    for (int nt = 0; nt < 2; ++nt)
      #pragma unroll
      for (int kq = 0; kq < 4; ++kq) {
        int rr = 16 * nt + lo, G = 4 * kq + hi;
        bf16x8 bf = *(const bf16x8*)&STb[rr][(G ^ (rr & 7)) << 3];
        acc_o[nt] = MFMA16(aq[kq], bf, acc_o[nt]);
      }
    #pragma unroll
    for (int nt = 0; nt < 4; ++nt)
      #pragma unroll
      for (int kq = 0; kq < 4; ++kq) {
        int rr = 16 * nt + lo, G = 4 * kq + hi;
        bf16x8 bf = *(const bf16x8*)&k_s[rr][(G ^ (rr & 7)) << 3];
        sacc[nt] = MFMA16(aq[kq], bf, sacc[nt]);
      }
    #pragma unroll
    for (int nt = 0; nt < 4; ++nt)
      #pragma unroll
      for (int r = 0; r < 4; ++r) {
        int c = 16 * wid + 4 * hi + r;
        int cp = 16 * nt + lo;
        float v = (cp <= c) ? sacc[nt][r] : 0.0f;
        sc_s[c][(((cp >> 3) ^ (c & 7)) << 3) | (cp & 7)] = (__bf16)v;
      }
    asm volatile("" ::: "memory");
    #pragma unroll
    for (int nt = 0; nt < 2; ++nt)
      #pragma unroll
      for (int kq = 0; kq < 2; ++kq) {
        int rA = 16 * wid + lo, GA = 4 * kq + hi;
        bf16x8 af = *(const bf16x8*)&sc_s[rA][(GA ^ (rA & 7)) << 3];
        int rB = 16 * nt + lo;
        bf16x8 bf = *(const bf16x8*)&vT_s[rB][(GA ^ (rB & 7)) << 3];
        acc_o[nt] = MFMA16(af, bf, acc_o[nt]);
      }
    #pragma unroll
    for (int nt = 0; nt < 2; ++nt)
      #pragma unroll
      for (int r = 0; r < 4; ++r) {
        int c = 16 * wid + 4 * hi + r;
        oh[(size_t)(s0 + c) * 4096 + 16 * nt + lo] = (__bf16)acc_o[nt][r];
      }
    __syncthreads();

    bf16x8 bu[2][2];
    #pragma unroll
    for (int q = 0; q < 2; ++q) {
      int dk = 16 * (2 * wid + q) + lo;
      #pragma unroll
      for (int kq = 0; kq < 2; ++kq) {
        bf16x8 tmp;
        #pragma unroll
        for (int j = 0; j < 8; ++j) {
          int c = 32 * kq + 8 * hi + j;
          tmp[j] = k_s[c][(((dk >> 3) ^ (c & 7)) << 3) | (dk & 7)];
        }
        bu[q][kq] = tmp;
      }
    }
    #pragma unroll
    for (int mt = 0; mt < 2; ++mt)
      #pragma unroll
      for (int kq = 0; kq < 2; ++kq) {
        int rA = 16 * mt + lo, GA = 4 * kq + hi;
        bf16x8 av = *(const bf16x8*)&vT_s[rA][(GA ^ (rA & 7)) << 3];
        #pragma unroll
        for (int q = 0; q < 2; ++q)
          st[mt][q] = MFMA16(av, bu[q][kq], st[mt][q]);
      }
    #pragma unroll
    for (int mt = 0; mt < 2; ++mt)
      #pragma unroll
      for (int q = 0; q < 2; ++q) {
        int dk = 16 * (2 * wid + q) + lo;
        #pragma unroll
        for (int r = 0; r < 4; ++r) {
          int dvr = 16 * mt + 4 * hi + r;
          STb[dvr][(((dk >> 3) ^ (dvr & 7)) << 3) | (dk & 7)] = (__bf16)st[mt][q][r];
        }
      }
    __syncthreads();
  }
}

// ---------------- launch ----------------
extern "C" void kernel_launch(void* const* d_in, const int* in_sizes, int n_in,
                              void* d_out, int out_size, void* d_ws, size_t ws_size,
                              hipStream_t stream) {
  (void)in_sizes; (void)n_in; (void)out_size; (void)ws_size;
  const float* hs   = (const float*)d_in[0];
  const float* cosT = (const float*)d_in[1];
  const float* sinT = (const float*)d_in[2];
  const float* Wq   = (const float*)d_in[3];
  const float* Wk   = (const float*)d_in[4];
  const float* Wv   = (const float*)d_in[5];
  const float* Wo   = (const float*)d_in[6];
  const float* fmq  = (const float*)d_in[7];
  const float* fmk  = (const float*)d_in[8];
  float* out = (float*)d_out;
  char* ws = (char*)d_ws;

  hipFuncSetAttribute((const void*)gemm256_kernel<float, 0>,
                      hipFuncAttributeMaxDynamicSharedMemorySize, 131072);
  hipFuncSetAttribute((const void*)gemm256_kernel<__bf16, 1>,
                      hipFuncAttributeMaxDynamicSharedMemorySize, 131072);
  hipFuncSetAttribute((const void*)gemm256_kernel<__bf16, 2>,
                      hipFuncAttributeMaxDynamicSharedMemorySize, 131072);

  const size_t MB = 1024ull * 1024ull;
  __bf16* Xb   = (__bf16*)(ws + 0);
  __bf16* qfb  = (__bf16*)(ws + 0);
  __bf16* kfb  = (__bf16*)(ws + 34 * MB);
  __bf16* Wqt  = (__bf16*)(ws + 70 * MB);
  __bf16* ob   = (__bf16*)(ws + 70 * MB);
  __bf16* Wkt  = (__bf16*)(ws + 104 * MB);
  __bf16* Wvt  = (__bf16*)(ws + 119 * MB);
  __bf16* Wot  = (__bf16*)(ws + 140 * MB);
  __bf16* ropq = (__bf16*)(ws + 170 * MB);
  __bf16* ropk = (__bf16*)(ws + 238 * MB);
  __bf16* vpb  = (__bf16*)(ws + 272 * MB);

  convert_kernel<<<28672, 256, 0, stream>>>(hs, Xb, (size_t)8192 * 3584 / 4);
  transpose_kernel<<<dim3(128, 112), 256, 0, stream>>>(Wq, Wqt, 3584, 4096);
  transpose_kernel<<<dim3(64, 112),  256, 0, stream>>>(Wk, Wkt, 3584, 2048);
  transpose_kernel<<<dim3(64, 112),  256, 0, stream>>>(Wv, Wvt, 3584, 2048);
  transpose_kernel<<<dim3(112, 128), 256, 0, stream>>>(Wo, Wot, 4096, 3584);

  gemm256_kernel<__bf16, 1><<<dim3(16, 32), 512, 131072, stream>>>(
      Xb, Wqt, ropq, 8192, 4096, 3584, cosT, sinT, 16);
  gemm256_kernel<__bf16, 1><<<dim3(8, 32),  512, 131072, stream>>>(
      Xb, Wkt, ropk, 8192, 2048, 3584, cosT, sinT, 8);
  gemm256_kernel<__bf16, 2><<<dim3(8, 32),  512, 131072, stream>>>(
      Xb, Wvt, vpb, 8192, 2048, 3584, nullptr, nullptr, 8);

  fm_kernel<<<dim3(32, 32), 256, 0, stream>>>(ropq, fmq, qfb, 16, 0.08838834764831845f);
  fm_kernel<<<dim3(32, 32), 256, 0, stream>>>(ropk, fmk, kfb, 8, 1.0f);

  attn_kernel<<<256, 256, 0, stream>>>(qfb, kfb, vpb, ob);

  gemm256_kernel<float, 0><<<dim3(14, 32), 512, 131072, stream>>>(
      ob, Wot, out, 8192, 3584, 4096, nullptr, nullptr, 0);
}

// Round 8
// 930.050 us; speedup vs baseline: 1.1851x; 1.0153x over previous
//
#include <hip/hip_runtime.h>

// ---------------- types / helpers ----------------
typedef float  f32x4  __attribute__((ext_vector_type(4)));
typedef __bf16 bf16x4 __attribute__((ext_vector_type(4)));
typedef __bf16 bf16x8 __attribute__((ext_vector_type(8)));

#define MFMA16(a,b,c) __builtin_amdgcn_mfma_f32_16x16x32_bf16((a),(b),(c),0,0,0)

__device__ __forceinline__ void async_copy16(void* lds, const void* gmem) {
  __builtin_amdgcn_global_load_lds(
      (const __attribute__((address_space(1))) void*)gmem,
      (__attribute__((address_space(3))) void*)lds, 16, 0, 0);
}

template<int N> __device__ __forceinline__ void vmcnt_gate() {
  if constexpr (N == 8) asm volatile("s_waitcnt vmcnt(8)" ::: "memory");
  else if constexpr (N == 6) asm volatile("s_waitcnt vmcnt(6)" ::: "memory");
  else if constexpr (N == 4) asm volatile("s_waitcnt vmcnt(4)" ::: "memory");
  else if constexpr (N == 2) asm volatile("s_waitcnt vmcnt(2)" ::: "memory");
  else if constexpr (N == 0) asm volatile("s_waitcnt vmcnt(0)" ::: "memory");
  __builtin_amdgcn_sched_barrier(0);
}

// counted lgkm wait: drains all ds_reads OLDER than the N just issued (rule #18 fences)
#define LGKM(N) do { __builtin_amdgcn_sched_barrier(0); \
                     asm volatile("s_waitcnt lgkmcnt(" #N ")" ::: "memory"); \
                     __builtin_amdgcn_sched_barrier(0); } while (0)

#define BARRIER do { __builtin_amdgcn_sched_barrier(0); \
                     __builtin_amdgcn_s_barrier(); \
                     __builtin_amdgcn_sched_barrier(0); } while (0)

// ---------------- convert f32 -> bf16 (vectorized x4) ----------------
__global__ __launch_bounds__(256) void convert_kernel(const float* __restrict__ in,
                                                      __bf16* __restrict__ out, size_t n4) {
  size_t i = (size_t)blockIdx.x * 256 + threadIdx.x;
  if (i >= n4) return;
  f32x4 v = *(const f32x4*)(in + i * 4);
  bf16x4 o;
  #pragma unroll
  for (int j = 0; j < 4; ++j) o[j] = (__bf16)v[j];
  *(bf16x4*)(out + i * 4) = o;
}

// ---------------- transpose + convert: in f32 (R,C) -> out bf16 (C,R) ----------------
__global__ __launch_bounds__(256) void transpose_kernel(const float* __restrict__ in,
                                                        __bf16* __restrict__ out, int R, int C) {
  __shared__ float tile[32][33];
  int bx = blockIdx.x, by = blockIdx.y;
  int tx = threadIdx.x & 31, ty0 = threadIdx.x >> 5;
  #pragma unroll
  for (int i = 0; i < 4; ++i) {
    int r = by * 32 + ty0 + i * 8;
    tile[ty0 + i * 8][tx] = in[(size_t)r * C + bx * 32 + tx];
  }
  __syncthreads();
  #pragma unroll
  for (int i = 0; i < 4; ++i) {
    int c = bx * 32 + ty0 + i * 8;
    out[(size_t)c * R + by * 32 + tx] = (__bf16)tile[tx][ty0 + i * 8];
  }
}

// ---------------- 256x256 pipelined bf16 GEMM (FROZEN at R5 best: 232us, 45% MfmaUtil) --
// K-loop (race-proven R3 schedule) + MODE epilogues: 0=plain, 1=RoPE fused (B colmap
// permute -> intra-thread butterfly), 2=V permuted store. See R3/R5 comments.

template<bool REMAP>
__device__ __forceinline__ void stage_q(__bf16* region, int qrow, const __bf16* src,
                                        int K, int w, int l) {
  int s = qrow + w * 8 + (l >> 3);
  int gr = REMAP ? (((s >> 5) << 4) | (s & 15) | (((s >> 4) & 1) << 7)) : s;
  async_copy16(region + (size_t)(qrow + w * 8) * 64,
               src + (size_t)gr * K + (((l & 7) ^ (s & 7)) << 3));
}

template<bool LATE, bool EARLY, bool NEXT, int G2, int G3, bool BMAP>
__device__ __forceinline__ void tile_body(__bf16* smem,
                                          const __bf16* Apan, const __bf16* Bpan,
                                          int K, int tau, int wm, int wn,
                                          int lo, int hi, int w, int l,
                                          bf16x8 (&aA)[4], bf16x8 (&aB)[4],
                                          bf16x8 (&bA)[4], bf16x8 (&bB)[4],
                                          f32x4 (&acc)[8][4]) {
  const int buf = tau & 1;
  __bf16* Ab = smem + buf * 32768;
  __bf16* Bb = Ab + 16384;
  __bf16* An = smem + (buf ^ 1) * 32768;
  __bf16* Bn = An + 16384;

  // ---- block0: R1 = aB <- a(h1,k0)[buf]; S0 = LATE; lgkm(4) drains R0; M0 = aA*bA
  #pragma unroll
  for (int t = 0; t < 4; ++t) {
    int ra = wm * 128 + 64 + t * 16 + lo;
    aB[t] = *(const bf16x8*)(Ab + (size_t)ra * 64 + ((hi ^ (ra & 7)) << 3));
  }
  if constexpr (LATE) {
    const __bf16* Ap1 = Apan + (size_t)(tau + 1) * 64;
    stage_q<false>(An, 64,  Ap1, K, w, l);   // A q1
    stage_q<false>(An, 192, Ap1, K, w, l);   // A q3
  }
  LGKM(4);
  __builtin_amdgcn_s_setprio(1);
  #pragma unroll
  for (int mt = 0; mt < 4; ++mt)
    #pragma unroll
    for (int nt = 0; nt < 4; ++nt)
      acc[mt][nt] = MFMA16(aA[mt], bA[nt], acc[mt][nt]);
  __builtin_amdgcn_s_setprio(0);
  BARRIER;

  // ---- block1: R2 = aA <- a(h0,k1), bB <- b(k1) [buf]; lgkm(8) drains R1; M1 = aB*bA
  #pragma unroll
  for (int t = 0; t < 4; ++t) {
    int ra = wm * 128 + t * 16 + lo;
    aA[t] = *(const bf16x8*)(Ab + (size_t)ra * 64 + (((4 + hi) ^ (ra & 7)) << 3));
  }
  #pragma unroll
  for (int t = 0; t < 4; ++t) {
    int rb = wn * 64 + t * 16 + lo;
    bB[t] = *(const bf16x8*)(Bb + (size_t)rb * 64 + (((4 + hi) ^ (rb & 7)) << 3));
  }
  LGKM(8);
  __builtin_amdgcn_s_setprio(1);
  #pragma unroll
  for (int mt = 0; mt < 4; ++mt)
    #pragma unroll
    for (int nt = 0; nt < 4; ++nt)
      acc[4 + mt][nt] = MFMA16(aB[mt], bA[nt], acc[4 + mt][nt]);
  __builtin_amdgcn_s_setprio(0);
  BARRIER;

  // ---- block2: R3 = aB <- a(h1,k1)[buf]; lgkm(4) drains R2; M2 = aA*bB;
  //      G2 gate BEFORE bar2 (cross-wave: EARLY(tau+1) landed for everyone)
  #pragma unroll
  for (int t = 0; t < 4; ++t) {
    int ra = wm * 128 + 64 + t * 16 + lo;
    aB[t] = *(const bf16x8*)(Ab + (size_t)ra * 64 + (((4 + hi) ^ (ra & 7)) << 3));
  }
  LGKM(4);
  __builtin_amdgcn_s_setprio(1);
  #pragma unroll
  for (int mt = 0; mt < 4; ++mt)
    #pragma unroll
    for (int nt = 0; nt < 4; ++nt)
      acc[mt][nt] = MFMA16(aA[mt], bB[nt], acc[mt][nt]);
  __builtin_amdgcn_s_setprio(0);
  if constexpr (G2 >= 0) vmcnt_gate<G2>();
  BARRIER;

  // ---- block3: R0' = aA <- a(h0,k0), bA <- b(k0) [nbuf] (NEXT); S3 = EARLY(tau+2 -> buf);
  //      lgkm(8|0) drains R3; M3 = aB*bB; G3 gate BEFORE bar3 (LATE landed for everyone)
  if constexpr (NEXT) {
    #pragma unroll
    for (int t = 0; t < 4; ++t) {
      int ra = wm * 128 + t * 16 + lo;
      aA[t] = *(const bf16x8*)(An + (size_t)ra * 64 + ((hi ^ (ra & 7)) << 3));
    }
    #pragma unroll
    for (int t = 0; t < 4; ++t) {
      int rb = wn * 64 + t * 16 + lo;
      bA[t] = *(const bf16x8*)(Bn + (size_t)rb * 64 + ((hi ^ (rb & 7)) << 3));
    }
  }
  if constexpr (EARLY) {
    const __bf16* Ap2 = Apan + (size_t)(tau + 2) * 64;
    const __bf16* Bp2 = Bpan + (size_t)(tau + 2) * 64;
    stage_q<false>(Ab, 0,   Ap2, K, w, l);   // A q0
    stage_q<false>(Ab, 128, Ap2, K, w, l);   // A q2
    stage_q<BMAP>(Bb, 0,   Bp2, K, w, l);    // B q0
    stage_q<BMAP>(Bb, 64,  Bp2, K, w, l);    // B q1
    stage_q<BMAP>(Bb, 128, Bp2, K, w, l);    // B q2
    stage_q<BMAP>(Bb, 192, Bp2, K, w, l);    // B q3
  }
  if constexpr (NEXT) LGKM(8); else LGKM(0);
  __builtin_amdgcn_s_setprio(1);
  #pragma unroll
  for (int mt = 0; mt < 4; ++mt)
    #pragma unroll
    for (int nt = 0; nt < 4; ++nt)
      acc[4 + mt][nt] = MFMA16(aB[mt], bB[nt], acc[4 + mt][nt]);
  __builtin_amdgcn_s_setprio(0);
  if constexpr (G3 >= 0) vmcnt_gate<G3>();
  BARRIER;
}

template <typename CT, int MODE>
__global__ __launch_bounds__(512, 2) void gemm256_kernel(const __bf16* __restrict__ A,
                                                         const __bf16* __restrict__ Bt,
                                                         CT* __restrict__ C, int M, int N, int K,
                                                         const float* __restrict__ cosT,
                                                         const float* __restrict__ sinT,
                                                         int Hh) {
  extern __shared__ __bf16 smem[];
  constexpr bool BMAP = (MODE == 1);

  // XCD-bijective block swizzle (all grids have nwg % 8 == 0)
  const int gx = gridDim.x;
  const int nwg = gx * gridDim.y;
  const int wg = blockIdx.y * gx + blockIdx.x;
  const int qq = nwg >> 3;
  const int id2 = (wg & 7) * qq + (wg >> 3);
  const int m0 = (id2 / gx) * 256, n0 = (id2 % gx) * 256;

  const int tid = threadIdx.x;
  const int l = tid & 63, w = tid >> 6;
  const int lo = l & 15, hi = l >> 4;
  const int wm = w >> 2, wn = w & 3;

  const __bf16* Apan = A + (size_t)m0 * K;
  const __bf16* Bpan = Bt + (size_t)n0 * K;

  f32x4 acc[8][4] = {};
  bf16x8 aA[4], aB[4], bA[4], bB[4];

  // prologue: stage tile0 (8 quanta) + tile1 (EARLY order first, LATE last);
  // vmcnt(8) = tile0 landed (per-wave) BEFORE barrier -> cross-wave visible after.
  stage_q<false>(smem,          0,   Apan, K, w, l);
  stage_q<false>(smem,          128, Apan, K, w, l);
  stage_q<BMAP>(smem + 16384,  0,   Bpan, K, w, l);
  stage_q<BMAP>(smem + 16384,  64,  Bpan, K, w, l);
  stage_q<BMAP>(smem + 16384,  128, Bpan, K, w, l);
  stage_q<BMAP>(smem + 16384,  192, Bpan, K, w, l);
  stage_q<false>(smem,          64,  Apan, K, w, l);
  stage_q<false>(smem,          192, Apan, K, w, l);
  stage_q<false>(smem + 32768,  0,   Apan + 64, K, w, l);
  stage_q<false>(smem + 32768,  128, Apan + 64, K, w, l);
  stage_q<BMAP>(smem + 49152,  0,   Bpan + 64, K, w, l);
  stage_q<BMAP>(smem + 49152,  64,  Bpan + 64, K, w, l);
  stage_q<BMAP>(smem + 49152,  128, Bpan + 64, K, w, l);
  stage_q<BMAP>(smem + 49152,  192, Bpan + 64, K, w, l);
  stage_q<false>(smem + 32768,  64,  Apan + 64, K, w, l);
  stage_q<false>(smem + 32768,  192, Apan + 64, K, w, l);
  vmcnt_gate<8>();
  BARRIER;

  #pragma unroll
  for (int t = 0; t < 4; ++t) {
    int ra = wm * 128 + t * 16 + lo;
    aA[t] = *(const bf16x8*)(smem + (size_t)ra * 64 + ((hi ^ (ra & 7)) << 3));
  }
  #pragma unroll
  for (int t = 0; t < 4; ++t) {
    int rb = wn * 64 + t * 16 + lo;
    bA[t] = *(const bf16x8*)(smem + 16384 + (size_t)rb * 64 + ((hi ^ (rb & 7)) << 3));
  }

  const int T = K >> 6;
  tile_body<false, true,  true,  2,  6, BMAP>(smem, Apan, Bpan, K, 0,     wm, wn, lo, hi, w, l, aA, aB, bA, bB, acc);
  for (int tau = 1; tau < T - 2; ++tau)
    tile_body<true, true,  true,  2,  6, BMAP>(smem, Apan, Bpan, K, tau,   wm, wn, lo, hi, w, l, aA, aB, bA, bB, acc);
  tile_body<true,  false, true,  2,  0, BMAP>(smem, Apan, Bpan, K, T - 2, wm, wn, lo, hi, w, l, aA, aB, bA, bB, acc);
  tile_body<false, false, false, -1, -1, BMAP>(smem, Apan, Bpan, K, T - 1, wm, wn, lo, hi, w, l, aA, aB, bA, bB, acc);

  if constexpr (MODE == 0) {
    // plain row-major C
    #pragma unroll
    for (int mt = 0; mt < 8; ++mt)
      #pragma unroll
      for (int nt = 0; nt < 4; ++nt) {
        int col = n0 + wn * 64 + nt * 16 + lo;
        #pragma unroll
        for (int r = 0; r < 4; ++r) {
          int row = m0 + wm * 128 + mt * 16 + 4 * hi + r;
          C[(size_t)row * N + col] = (CT)acc[mt][nt][r];
        }
      }
  } else if constexpr (MODE == 2) {
    // V: store to (b, kv, s, d); n-block == one KV head
    const int kv = n0 >> 8;
    #pragma unroll
    for (int mt = 0; mt < 8; ++mt)
      #pragma unroll
      for (int nt = 0; nt < 4; ++nt) {
        int col = wn * 64 + nt * 16 + lo;
        #pragma unroll
        for (int r = 0; r < 4; ++r) {
          int row = m0 + wm * 128 + mt * 16 + 4 * hi + r;
          int bb = row >> 12, sdx = row & 4095;
          C[(((size_t)(bb * Hh + kv)) * 4096 + sdx) * 256 + col] = (CT)acc[mt][nt][r];
        }
      }
  } else {
    // MODE 1: fused RoPE + store to (b, h, s, d). acc cols are colmap-permuted:
    // pair (nt, nt+1) = (d, d+128) with d = (2*wn + (nt>>1))*16 + lo.
    const int hq = n0 >> 8;
    #pragma unroll
    for (int mt = 0; mt < 8; ++mt)
      #pragma unroll
      for (int ntp = 0; ntp < 4; ntp += 2) {
        int d = (2 * wn + (ntp >> 1)) * 16 + lo;
        #pragma unroll
        for (int r = 0; r < 4; ++r) {
          int row = m0 + wm * 128 + mt * 16 + 4 * hi + r;
          int bb = row >> 12, sdx = row & 4095;
          float cc = cosT[(size_t)sdx * 128 + d];
          float ss = sinT[(size_t)sdx * 128 + d];
          float x1 = acc[mt][ntp][r], x2 = acc[mt][ntp + 1][r];
          size_t base = (((size_t)(bb * Hh + hq)) * 4096 + sdx) * 256;
          C[base + d]       = (CT)(x1 * cc - x2 * ss);
          C[base + d + 128] = (CT)(x1 * ss + x2 * cc);
        }
      }
  }
}

// ---------------- feature map ----------------
__global__ __launch_bounds__(256) void fm_kernel(const __bf16* __restrict__ rope,
                                                 const float* __restrict__ fm,
                                                 __bf16* __restrict__ out, int srcH, float scale) {
  __shared__ __bf16 fmT[64][256];  // [f][d] swizzled: group' = (d>>3) ^ (f&7)
  int bh = blockIdx.y;
  int h = bh & 15, b = bh >> 4;
  int s0 = blockIdx.x * 128;
  int tid = threadIdx.x, lane = tid & 63, wid = tid >> 6, hi = lane >> 4, lo = lane & 15;

  const float* fmh = fm + (size_t)h * 256 * 64;
  for (int i = tid; i < 256 * 64; i += 256) {
    int d = i >> 6, f = i & 63;
    fmT[f][(((d >> 3) ^ (f & 7)) << 3) | (d & 7)] = (__bf16)fmh[i];
  }
  __syncthreads();

  int srch = (srcH == 16) ? h : (h >> 1);
  const __bf16* abase = rope + ((size_t)(b * srcH + srch) * 4096 + s0 + 32 * wid) * 256;
  f32x4 acc[2][4] = {};
  for (int kk = 0; kk < 256; kk += 32) {
    bf16x8 a[2], bf[4];
    #pragma unroll
    for (int mt = 0; mt < 2; ++mt)
      a[mt] = *(const bf16x8*)(abase + (size_t)(16 * mt + lo) * 256 + kk + 8 * hi);
    const int G = (kk >> 3) + hi;
    #pragma unroll
    for (int nt = 0; nt < 4; ++nt) {
      int f = 16 * nt + lo;
      bf[nt] = *(const bf16x8*)&fmT[f][(G ^ (f & 7)) << 3];
    }
    #pragma unroll
    for (int mt = 0; mt < 2; ++mt)
      #pragma unroll
      for (int nt = 0; nt < 4; ++nt)
        acc[mt][nt] = MFMA16(a[mt], bf[nt], acc[mt][nt]);
  }

  size_t obase = ((size_t)(b * 16 + h) * 4096 + s0 + 32 * wid);
  #pragma unroll
  for (int mt = 0; mt < 2; ++mt) {
    #pragma unroll
    for (int r = 0; r < 4; ++r) {
      float z0 = acc[mt][0][r], z1 = acc[mt][1][r], z2 = acc[mt][2][r], z3 = acc[mt][3][r];
      float mx = fmaxf(fmaxf(z0, z1), fmaxf(z2, z3));
      float mn = fminf(fminf(z0, z1), fminf(z2, z3));
      #pragma unroll
      for (int off = 1; off < 16; off <<= 1) {
        mx = fmaxf(mx, __shfl_xor(mx, off));
        mn = fminf(mn, __shfl_xor(mn, off));
      }
      float ep0 = __expf(z0 - mx), ep1 = __expf(z1 - mx), ep2 = __expf(z2 - mx), ep3 = __expf(z3 - mx);
      float en0 = __expf(mn - z0), en1 = __expf(mn - z1), en2 = __expf(mn - z2), en3 = __expf(mn - z3);
      float sp = ep0 + ep1 + ep2 + ep3, sn = en0 + en1 + en2 + en3;
      #pragma unroll
      for (int off = 1; off < 16; off <<= 1) {
        sp += __shfl_xor(sp, off);
        sn += __shfl_xor(sn, off);
      }
      float rp = scale / sp, rn = scale / sn;
      int row = 16 * mt + 4 * hi + r;
      __bf16* op = out + (obase + row) * 128;
      op[0  + lo] = (__bf16)(ep0 * rp);  op[16 + lo] = (__bf16)(ep1 * rp);
      op[32 + lo] = (__bf16)(ep2 * rp);  op[48 + lo] = (__bf16)(ep3 * rp);
      op[64 + lo] = (__bf16)(en0 * rn);  op[80 + lo] = (__bf16)(en1 * rn);
      op[96 + lo] = (__bf16)(en2 * rn);  op[112 + lo] = (__bf16)(en3 * rn);
    }
  }
}

// ---------------- chunked linear attention (R8: software-pipelined) ----------------
// XCD swizzle (R7, kept): g = ((bid>>6)<<3)|(bid&7), dvb = (bid>>3)&7 -> dv-siblings
// share an XCD, q/k head-slices are L2-local.
// NEW: double-buffered K/V + prefetch. Iteration n prefetches chunk n+1 (K via
// global_load_lds into k_s[buf^1], V+q into registers) at the TOP, giving loads a
// full iteration to land. Syncs lightened (m201 idiom): mid = raw s_barrier (all
// pre-barrier LDS reads are register-consumed -> no drain needed); end = lgkm(0) +
// s_barrier. NO vmcnt drain in the loop: the vT_s write consumes vv(n+1), forcing a
// compiler counted vmcnt wait; FIFO vmcnt semantics (m135) => older K-stages drained
// too, per-wave BEFORE the end barrier (cross-wave visibility, R2 lesson).
// Hazards: k_s[buf^1] write at n-top vs its last readers (n-1 compute) fenced by
// n-1 end barrier; vT_s[buf^1] write (after mid barrier) vs n-1 readers likewise;
// sc_s is wave-private rows; STb read(5)/write(11) split by mid barrier.
// n=63 skips the dead ST-update + syncs.
__global__ __launch_bounds__(256) void attn_kernel(const __bf16* __restrict__ qf,
                                                   const __bf16* __restrict__ kf,
                                                   const __bf16* __restrict__ vp,
                                                   __bf16* __restrict__ o) {
  __shared__ __bf16 k_s[2][64][128];
  __shared__ __bf16 vT_s[2][32][64];
  __shared__ __bf16 sc_s[64][64];
  __shared__ __bf16 STb[32][128];

  int bid = blockIdx.x;
  int g   = ((bid >> 6) << 3) | (bid & 7);   // 0..31 = b*16 + h
  int dvb = (bid >> 3) & 7;
  int h = g & 15, b = g >> 4;
  int dv0 = dvb * 32;
  int tid = threadIdx.x, lane = tid & 63, wid = tid >> 6, hi = lane >> 4, lo = lane & 15;

  const __bf16* qh = qf + ((size_t)(b * 16 + h)) * 4096 * 128;
  const __bf16* kh = kf + ((size_t)(b * 16 + h)) * 4096 * 128;
  const __bf16* vh = vp + ((size_t)(b * 8 + (h >> 1))) * 4096 * 256 + dv0;
  __bf16* oh = o + ((size_t)b * 4096) * 4096 + h * 256 + dv0;

  {
    unsigned int* z = (unsigned int*)&STb[0][0];
    for (int i = tid; i < 2048; i += 256) z[i] = 0u;
  }
  f32x4 st[2][2] = {};

  const int vc = tid >> 2, vd8 = (tid & 3) * 8;
  bf16x8 aqN[4], aqC[4], vvN;

  // ---- prologue: K(0)->buf0, V(0)->reg, q(0)->reg; vT_s[0] write waits vv(0)
  // (FIFO => K(0) drained per-wave); lgkm(0)+barrier -> cross-wave visible.
  #pragma unroll
  for (int i = 0; i < 4; ++i) {
    int rb = (wid * 4 + i) * 4;
    int r = rb + (lane >> 4);
    int Glog = (lane & 15) ^ (r & 7);
    async_copy16(&k_s[0][rb][0], kh + (size_t)r * 128 + Glog * 8);
  }
  __builtin_amdgcn_sched_barrier(0);
  vvN = *(const bf16x8*)(vh + (size_t)vc * 256 + vd8);
  __builtin_amdgcn_sched_barrier(0);
  #pragma unroll
  for (int kq = 0; kq < 4; ++kq)
    aqN[kq] = *(const bf16x8*)(qh + (size_t)(16 * wid + lo) * 128 + 32 * kq + 8 * hi);
  __builtin_amdgcn_sched_barrier(0);
  #pragma unroll
  for (int j = 0; j < 8; ++j) {
    int dv = vd8 + j;
    vT_s[0][dv][(((vc >> 3) ^ (dv & 7)) << 3) | (vc & 7)] = vvN[j];
  }
  LGKM(0);
  BARRIER;

  for (int n = 0; n < 64; ++n) {
    const int buf = n & 1;
    const int s0 = n * 64;

    // consume q(n) (compiler waits the n-issued loads here), then prefetch n+1
    #pragma unroll
    for (int kq = 0; kq < 4; ++kq) aqC[kq] = aqN[kq];

    if (n < 63) {
      const int s1 = s0 + 64;
      #pragma unroll
      for (int i = 0; i < 4; ++i) {
        int rb = (wid * 4 + i) * 4;
        int r = rb + (lane >> 4);
        int Glog = (lane & 15) ^ (r & 7);
        async_copy16(&k_s[buf ^ 1][rb][0], kh + (size_t)(s1 + r) * 128 + Glog * 8);
      }
      __builtin_amdgcn_sched_barrier(0);
      vvN = *(const bf16x8*)(vh + (size_t)(s1 + vc) * 256 + vd8);
      __builtin_amdgcn_sched_barrier(0);
      #pragma unroll
      for (int kq = 0; kq < 4; ++kq)
        aqN[kq] = *(const bf16x8*)(qh + (size_t)(s1 + 16 * wid + lo) * 128 + 32 * kq + 8 * hi);
      __builtin_amdgcn_sched_barrier(0);
    }

    // ---- compute on buf: inter (q @ STb) + scores (q @ k)
    f32x4 acc_o[2] = {}, sacc[4] = {};
    #pragma unroll
    for (int nt = 0; nt < 2; ++nt)
      #pragma unroll
      for (int kq = 0; kq < 4; ++kq) {
        int rr = 16 * nt + lo, G = 4 * kq + hi;
        bf16x8 bf = *(const bf16x8*)&STb[rr][(G ^ (rr & 7)) << 3];
        acc_o[nt] = MFMA16(aqC[kq], bf, acc_o[nt]);
      }
    #pragma unroll
    for (int nt = 0; nt < 4; ++nt)
      #pragma unroll
      for (int kq = 0; kq < 4; ++kq) {
        int rr = 16 * nt + lo, G = 4 * kq + hi;
        bf16x8 bf = *(const bf16x8*)&k_s[buf][rr][(G ^ (rr & 7)) << 3];
        sacc[nt] = MFMA16(aqC[kq], bf, sacc[nt]);
      }
    // causal mask -> sc_s (wave-private 16-row band; intra-wave fence suffices)
    #pragma unroll
    for (int nt = 0; nt < 4; ++nt)
      #pragma unroll
      for (int r = 0; r < 4; ++r) {
        int c = 16 * wid + 4 * hi + r;
        int cp = 16 * nt + lo;
        float v = (cp <= c) ? sacc[nt][r] : 0.0f;
        sc_s[c][(((cp >> 3) ^ (c & 7)) << 3) | (cp & 7)] = (__bf16)v;
      }
    asm volatile("" ::: "memory");
    // intra: sc @ vT
    #pragma unroll
    for (int nt = 0; nt < 2; ++nt)
      #pragma unroll
      for (int kq = 0; kq < 2; ++kq) {
        int rA = 16 * wid + lo, GA = 4 * kq + hi;
        bf16x8 af = *(const bf16x8*)&sc_s[rA][(GA ^ (rA & 7)) << 3];
        int rB = 16 * nt + lo;
        bf16x8 bf = *(const bf16x8*)&vT_s[buf][rB][(GA ^ (rB & 7)) << 3];
        acc_o[nt] = MFMA16(af, bf, acc_o[nt]);
      }
    #pragma unroll
    for (int nt = 0; nt < 2; ++nt)
      #pragma unroll
      for (int r = 0; r < 4; ++r) {
        int c = 16 * wid + 4 * hi + r;
        oh[(size_t)(s0 + c) * 4096 + 16 * nt + lo] = (__bf16)acc_o[nt][r];
      }

    if (n == 63) break;   // ST update is dead on the last chunk

    BARRIER;  // mid: raw barrier (all pre-barrier LDS reads register-consumed)

    // ---- ST update: st += v^T @ k  (bu rebuilt from k_s[buf])
    bf16x8 bu[2][2];
    #pragma unroll
    for (int q = 0; q < 2; ++q) {
      int dk = 16 * (2 * wid + q) + lo;
      #pragma unroll
      for (int kq = 0; kq < 2; ++kq) {
        bf16x8 tmp;
        #pragma unroll
        for (int j = 0; j < 8; ++j) {
          int c = 32 * kq + 8 * hi + j;
          tmp[j] = k_s[buf][c][(((dk >> 3) ^ (c & 7)) << 3) | (dk & 7)];
        }
        bu[q][kq] = tmp;
      }
    }
    #pragma unroll
    for (int mt = 0; mt < 2; ++mt)
      #pragma unroll
      for (int kq = 0; kq < 2; ++kq) {
        int rA = 16 * mt + lo, GA = 4 * kq + hi;
        bf16x8 av = *(const bf16x8*)&vT_s[buf][rA][(GA ^ (rA & 7)) << 3];
        #pragma unroll
        for (int q = 0; q < 2; ++q)
          st[mt][q] = MFMA16(av, bu[q][kq], st[mt][q]);
      }
    #pragma unroll
    for (int mt = 0; mt < 2; ++mt)
      #pragma unroll
      for (int q = 0; q < 2; ++q) {
        int dk = 16 * (2 * wid + q) + lo;
        #pragma unroll
        for (int r = 0; r < 4; ++r) {
          int dvr = 16 * mt + 4 * hi + r;
          STb[dvr][(((dk >> 3) ^ (dvr & 7)) << 3) | (dk & 7)] = (__bf16)st[mt][q][r];
        }
      }
    // vT_s[buf^1] <- vv(n+1): compiler waits vv(n+1) => K(n+1) (older) drained
    #pragma unroll
    for (int j = 0; j < 8; ++j) {
      int dv = vd8 + j;
      vT_s[buf ^ 1][dv][(((vc >> 3) ^ (dv & 7)) << 3) | (vc & 7)] = vvN[j];
    }
    LGKM(0);   // ds_writes (STb, vT_s) visible cross-wave after barrier
    BARRIER;
  }
}

// ---------------- launch ----------------
extern "C" void kernel_launch(void* const* d_in, const int* in_sizes, int n_in,
                              void* d_out, int out_size, void* d_ws, size_t ws_size,
                              hipStream_t stream) {
  (void)in_sizes; (void)n_in; (void)out_size; (void)ws_size;
  const float* hs   = (const float*)d_in[0];
  const float* cosT = (const float*)d_in[1];
  const float* sinT = (const float*)d_in[2];
  const float* Wq   = (const float*)d_in[3];
  const float* Wk   = (const float*)d_in[4];
  const float* Wv   = (const float*)d_in[5];
  const float* Wo   = (const float*)d_in[6];
  const float* fmq  = (const float*)d_in[7];
  const float* fmk  = (const float*)d_in[8];
  float* out = (float*)d_out;
  char* ws = (char*)d_ws;

  hipFuncSetAttribute((const void*)gemm256_kernel<float, 0>,
                      hipFuncAttributeMaxDynamicSharedMemorySize, 131072);
  hipFuncSetAttribute((const void*)gemm256_kernel<__bf16, 1>,
                      hipFuncAttributeMaxDynamicSharedMemorySize, 131072);
  hipFuncSetAttribute((const void*)gemm256_kernel<__bf16, 2>,
                      hipFuncAttributeMaxDynamicSharedMemorySize, 131072);

  const size_t MB = 1024ull * 1024ull;
  __bf16* Xb   = (__bf16*)(ws + 0);
  __bf16* qfb  = (__bf16*)(ws + 0);
  __bf16* kfb  = (__bf16*)(ws + 34 * MB);
  __bf16* Wqt  = (__bf16*)(ws + 70 * MB);
  __bf16* ob   = (__bf16*)(ws + 70 * MB);
  __bf16* Wkt  = (__bf16*)(ws + 104 * MB);
  __bf16* Wvt  = (__bf16*)(ws + 119 * MB);
  __bf16* Wot  = (__bf16*)(ws + 140 * MB);
  __bf16* ropq = (__bf16*)(ws + 170 * MB);
  __bf16* ropk = (__bf16*)(ws + 238 * MB);
  __bf16* vpb  = (__bf16*)(ws + 272 * MB);

  convert_kernel<<<28672, 256, 0, stream>>>(hs, Xb, (size_t)8192 * 3584 / 4);
  transpose_kernel<<<dim3(128, 112), 256, 0, stream>>>(Wq, Wqt, 3584, 4096);
  transpose_kernel<<<dim3(64, 112),  256, 0, stream>>>(Wk, Wkt, 3584, 2048);
  transpose_kernel<<<dim3(64, 112),  256, 0, stream>>>(Wv, Wvt, 3584, 2048);
  transpose_kernel<<<dim3(112, 128), 256, 0, stream>>>(Wo, Wot, 4096, 3584);

  gemm256_kernel<__bf16, 1><<<dim3(16, 32), 512, 131072, stream>>>(
      Xb, Wqt, ropq, 8192, 4096, 3584, cosT, sinT, 16);
  gemm256_kernel<__bf16, 1><<<dim3(8, 32),  512, 131072, stream>>>(
      Xb, Wkt, ropk, 8192, 2048, 3584, cosT, sinT, 8);
  gemm256_kernel<__bf16, 2><<<dim3(8, 32),  512, 131072, stream>>>(
      Xb, Wvt, vpb, 8192, 2048, 3584, nullptr, nullptr, 8);

  fm_kernel<<<dim3(32, 32), 256, 0, stream>>>(ropq, fmq, qfb, 16, 0.08838834764831845f);
  fm_kernel<<<dim3(32, 32), 256, 0, stream>>>(ropk, fmk, kfb, 8, 1.0f);

  attn_kernel<<<256, 256, 0, stream>>>(qfb, kfb, vpb, ob);

  gemm256_kernel<float, 0><<<dim3(14, 32), 512, 131072, stream>>>(
      ob, Wot, out, 8192, 3584, 4096, nullptr, nullptr, 0);
}